// Round 9
// baseline (480.061 us; speedup 1.0000x reference)
//
#include <hip/hip_runtime.h>
#include <hip/hip_bf16.h>

#define N_NODES 100000
#define E_EDGES 800000
#define E2 (E_EDGES + N_NODES)   // 900000 edges incl. self loops
#define FIN 128
#define HD 64
#define NH 8
#define NG 128
#define NC 10
#define SLOPE 0.2f
#define SELF_FLAG 0x40000000
#define SRC_MASK  0x3FFFFFFF
#define NSCAN_BLK 391            // ceil(N/256)
#define NBLK64 1563              // ceil(N/64)
#define GB 16                    // blocks per graph in fused gcn+readout
#define ECAP 256                 // LDS beta slots per node in edge_att
#define NPW 4                    // nodes per wave in edge_att
#define EA_BLKS 6250             // N / (4 waves * NPW)

// union-kernel geometry
#define U1_STRIPES 261
#define U1_GRID (2 + U1_STRIPES * 7)     // 1829: 2 wprep + 783 gemm + 1044 hist
#define U1_HISTB (U1_STRIPES * 4)        // 1044
#define T1 (U1_STRIPES * 3)              // 783 gemm tiles in U1
#define U2_STRIPES 391
#define U2_GRID (U2_STRIPES * 11)        // 4301: 3128 scatter + 782 gemm + 391 selfmark

typedef unsigned short bfu;

__device__ __forceinline__ float lrelu(float x) { return x > 0.f ? x : SLOPE * x; }

__device__ __forceinline__ bfu f2bf(float f) {
    unsigned int u = __float_as_uint(f);
    u += 0x7FFFu + ((u >> 16) & 1u);          // round-to-nearest-even
    return (bfu)(u >> 16);
}
__device__ __forceinline__ float bf2f(bfu s) {
    return __uint_as_float(((unsigned int)s) << 16);
}
__device__ __forceinline__ float bflo(unsigned int u) { return __uint_as_float(u << 16); }
__device__ __forceinline__ float bfhi(unsigned int u) { return __uint_as_float(u & 0xFFFF0000u); }

// ---------------------------------------------------------------------------
// Tiled node GEMM body: 64 nodes/tile, thread = 4 nodes x 4 outputs.
// smem layout: Ws[KH*64] | rows[64*(KIN+4)]
// ---------------------------------------------------------------------------
template<typename TIN, int KIN, int MODE>
__device__ __forceinline__
void gemm_tile_body(float* smem, int tile,
                    const TIN* __restrict__ in, const float* __restrict__ W,
                    bfu* __restrict__ outB,
                    const float* __restrict__ a_s, const float* __restrict__ a_d,
                    float* __restrict__ es, float* __restrict__ ed)
{
    constexpr int KH = (KIN > 64) ? 64 : KIN;     // K chunk staged at once
    constexpr int RS = KIN + 4;                   // rows stride (floats), %4==0
    float* Ws   = smem;                           // KH*64
    float* rows = smem + KH * 64;                 // 64*RS
    int t = threadIdx.x;
    int base = tile * 64;

    // ---- stage input rows (fp32) ----
    if constexpr (sizeof(TIN) == 4) {
        constexpr int RQ = KIN / 4;
        for (int i = t; i < 64 * RQ; i += 256) {
            int r = i / RQ, c = (i % RQ) * 4;
            int n = base + r;
            float4 v = make_float4(0.f, 0.f, 0.f, 0.f);
            if (n < N_NODES) v = *(const float4*)((const float*)in + (size_t)n * KIN + c);
            *(float4*)(rows + r * RS + c) = v;
        }
    } else {
        constexpr int RQ = KIN / 8;
        for (int i = t; i < 64 * RQ; i += 256) {
            int r = i / RQ, c = (i % RQ) * 8;
            int n = base + r;
            uint4 v = make_uint4(0, 0, 0, 0);
            if (n < N_NODES) v = *(const uint4*)((const bfu*)in + (size_t)n * KIN + c);
            float* dp = rows + r * RS + c;
            *(float4*)dp       = make_float4(bflo(v.x), bfhi(v.x), bflo(v.y), bfhi(v.y));
            *(float4*)(dp + 4) = make_float4(bflo(v.z), bfhi(v.z), bflo(v.w), bfhi(v.w));
        }
    }

    int tr = t >> 4, tc = t & 15;
    float acc[4][4] = {};
    const float4* R4 = (const float4*)rows;       // stride RS/4 float4s

    for (int h = 0; h < KIN / KH; ++h) {
        __syncthreads();                          // rows ready (h=0) / Ws free (h>0)
        {
            const float4* Wv = (const float4*)(W + (size_t)h * KH * 64);
            float4* Wsv4 = (float4*)Ws;
            for (int i = t; i < KH * 16; i += 256) Wsv4[i] = Wv[i];
        }
        __syncthreads();
        const float4* Wsv = (const float4*)Ws;
#pragma unroll 2
        for (int k = 0; k < KH; k += 4) {
            float4 w0 = Wsv[(k + 0) * 16 + tc];
            float4 w1 = Wsv[(k + 1) * 16 + tc];
            float4 w2 = Wsv[(k + 2) * 16 + tc];
            float4 w3 = Wsv[(k + 3) * 16 + tc];
            int kq = (h * KH + k) >> 2;
#pragma unroll
            for (int i = 0; i < 4; ++i) {
                float4 r = R4[(tr * 4 + i) * (RS / 4) + kq];
                acc[i][0] = fmaf(r.x, w0.x, fmaf(r.y, w1.x, fmaf(r.z, w2.x, fmaf(r.w, w3.x, acc[i][0]))));
                acc[i][1] = fmaf(r.x, w0.y, fmaf(r.y, w1.y, fmaf(r.z, w2.y, fmaf(r.w, w3.y, acc[i][1]))));
                acc[i][2] = fmaf(r.x, w0.z, fmaf(r.y, w1.z, fmaf(r.z, w2.z, fmaf(r.w, w3.z, acc[i][2]))));
                acc[i][3] = fmaf(r.x, w0.w, fmaf(r.y, w1.w, fmaf(r.z, w2.w, fmaf(r.w, w3.w, acc[i][3]))));
            }
        }
    }

    int j0 = tc * 4;
#pragma unroll
    for (int i = 0; i < 4; ++i) {
        int n = base + tr * 4 + i;
        if (n < N_NODES) {
            ushort4 ov;
            ov.x = f2bf(acc[i][0]); ov.y = f2bf(acc[i][1]);
            ov.z = f2bf(acc[i][2]); ov.w = f2bf(acc[i][3]);
            *(ushort4*)(outB + (size_t)n * 64 + j0) = ov;
        }
    }
    if (MODE == 1) {
        float s0[4], s1[4];
#pragma unroll
        for (int i = 0; i < 4; ++i) {
            float pes = 0.f, ped = 0.f;
#pragma unroll
            for (int q = 0; q < 4; ++q) {
                pes = fmaf(acc[i][q], a_s[j0 + q], pes);
                ped = fmaf(acc[i][q], a_d[j0 + q], ped);
            }
            pes += __shfl_xor(pes, 1, 64);
            ped += __shfl_xor(ped, 1, 64);
            s0[i] = pes; s1[i] = ped;
        }
        if ((tc & 1) == 0) {
            int h = tc >> 1;
#pragma unroll
            for (int i = 0; i < 4; ++i) {
                int n = base + tr * 4 + i;
                if (n < N_NODES) {
                    es[n * NH + h] = s0[i];
                    ed[n * NH + h] = s1[i];
                }
            }
        }
    }
}

// ---------------------------------------------------------------------------
// GAT aggregate phase (device body): block covers nodes [base, base+64).
// Wave w handles 16 nodes via slot-per-node (4 at a time).  Output: fp32 rows
// in LDS (stride 68) and optionally bf16 row to global outB.
// ---------------------------------------------------------------------------
template<int ELU, int GSTORE>
__device__ __forceinline__
void agg_phase(float* rows, int base,
               const int* __restrict__ offs, const int* __restrict__ csr,
               const float* __restrict__ es, const float* __restrict__ ed,
               const bfu* __restrict__ hsrcB, const float* __restrict__ bias,
               bfu* __restrict__ outB)
{
    int t = threadIdx.x;
    int w = t >> 6, lane = t & 63;
    int slot = lane >> 4, fl = lane & 15, h = fl >> 1;
    float4 bv = *(const float4*)(bias + fl * 4);
#pragma unroll
    for (int jj = 0; jj < 4; ++jj) {
        int local = w * 16 + jj * 4 + slot;
        int n = base + local;
        if (n >= N_NODES) {
            *(float4*)(rows + local * 68 + fl * 4) = make_float4(0.f, 0.f, 0.f, 0.f);
            continue;
        }
        int beg = offs[n], end = offs[n + 1];
        float edv = ed[n * NH + h];
        float den = 0.f;
        float4 acc = make_float4(0.f, 0.f, 0.f, 0.f);
        int p = beg;
        for (; p + 1 < end; p += 2) {
            int s0 = csr[p] & SRC_MASK;
            int s1 = csr[p + 1] & SRC_MASK;
            float ex0 = __expf(lrelu(es[s0 * NH + h] + edv));
            float ex1 = __expf(lrelu(es[s1 * NH + h] + edv));
            den += ex0 + ex1;
            ushort4 ra = *(const ushort4*)(hsrcB + (size_t)s0 * HD + fl * 4);
            ushort4 rb = *(const ushort4*)(hsrcB + (size_t)s1 * HD + fl * 4);
            acc.x = fmaf(bf2f(ra.x), ex0, fmaf(bf2f(rb.x), ex1, acc.x));
            acc.y = fmaf(bf2f(ra.y), ex0, fmaf(bf2f(rb.y), ex1, acc.y));
            acc.z = fmaf(bf2f(ra.z), ex0, fmaf(bf2f(rb.z), ex1, acc.z));
            acc.w = fmaf(bf2f(ra.w), ex0, fmaf(bf2f(rb.w), ex1, acc.w));
        }
        if (p < end) {
            int s = csr[p] & SRC_MASK;
            float ex = __expf(lrelu(es[s * NH + h] + edv));
            den += ex;
            ushort4 rb = *(const ushort4*)(hsrcB + (size_t)s * HD + fl * 4);
            acc.x = fmaf(bf2f(rb.x), ex, acc.x);
            acc.y = fmaf(bf2f(rb.y), ex, acc.y);
            acc.z = fmaf(bf2f(rb.z), ex, acc.z);
            acc.w = fmaf(bf2f(rb.w), ex, acc.w);
        }
        float inv = 1.f / (den + 1e-16f);
        float v0 = acc.x * inv + bv.x;
        float v1 = acc.y * inv + bv.y;
        float v2 = acc.z * inv + bv.z;
        float v3 = acc.w * inv + bv.w;
        if (ELU) {
            v0 = v0 > 0.f ? v0 : (__expf(v0) - 1.f);
            v1 = v1 > 0.f ? v1 : (__expf(v1) - 1.f);
            v2 = v2 > 0.f ? v2 : (__expf(v2) - 1.f);
            v3 = v3 > 0.f ? v3 : (__expf(v3) - 1.f);
        }
        *(float4*)(rows + local * 68 + fl * 4) = make_float4(v0, v1, v2, v3);
        if (GSTORE) {
            ushort4 ov;
            ov.x = f2bf(v0); ov.y = f2bf(v1); ov.z = f2bf(v2); ov.w = f2bf(v3);
            *(ushort4*)(outB + (size_t)n * HD + fl * 4) = ov;
        }
    }
}

// ---------------------------------------------------------------------------
// FUSED A: GAT1 aggregate (ELU) -> LDS rows -> GAT2 gemm (K=64) + es2/ed2.
// H1 never touches global memory.  smem: Ws[4096] | rows[64*68] = 33 KB.
// ---------------------------------------------------------------------------
__global__ __launch_bounds__(256)
void agg1_gemm2(const int* __restrict__ offs, const int* __restrict__ csr,
                const float* __restrict__ es, const float* __restrict__ ed,
                const bfu* __restrict__ B0, const float* __restrict__ b1,
                const float* __restrict__ W2,
                bfu* __restrict__ outB /*BH1*/,
                const float* __restrict__ as2, const float* __restrict__ ad2,
                float* __restrict__ es2, float* __restrict__ ed2)
{
    __shared__ __align__(16) float smem[4096 + 64 * 68];
    float* Ws   = smem;
    float* rows = smem + 4096;
    int t = threadIdx.x;
    int base = blockIdx.x * 64;
    {   // stage W2 early (independent of aggregate phase)
        const float4* Wv = (const float4*)W2;
        float4* Wsv4 = (float4*)Ws;
        for (int i = t; i < 1024; i += 256) Wsv4[i] = Wv[i];
    }
    agg_phase<1, 0>(rows, base, offs, csr, es, ed, B0, b1, nullptr);
    __syncthreads();
    // ---- gemm phase (rows pre-filled, K=64) ----
    int tr = t >> 4, tc = t & 15;
    float acc[4][4] = {};
    const float4* R4 = (const float4*)rows;       // stride 17 float4s
    const float4* Wsv = (const float4*)Ws;
#pragma unroll 2
    for (int k = 0; k < 64; k += 4) {
        float4 w0 = Wsv[(k + 0) * 16 + tc];
        float4 w1 = Wsv[(k + 1) * 16 + tc];
        float4 w2 = Wsv[(k + 2) * 16 + tc];
        float4 w3 = Wsv[(k + 3) * 16 + tc];
        int kq = k >> 2;
#pragma unroll
        for (int i = 0; i < 4; ++i) {
            float4 r = R4[(tr * 4 + i) * 17 + kq];
            acc[i][0] = fmaf(r.x, w0.x, fmaf(r.y, w1.x, fmaf(r.z, w2.x, fmaf(r.w, w3.x, acc[i][0]))));
            acc[i][1] = fmaf(r.x, w0.y, fmaf(r.y, w1.y, fmaf(r.z, w2.y, fmaf(r.w, w3.y, acc[i][1]))));
            acc[i][2] = fmaf(r.x, w0.z, fmaf(r.y, w1.z, fmaf(r.z, w2.z, fmaf(r.w, w3.z, acc[i][2]))));
            acc[i][3] = fmaf(r.x, w0.w, fmaf(r.y, w1.w, fmaf(r.z, w2.w, fmaf(r.w, w3.w, acc[i][3]))));
        }
    }
    int j0 = tc * 4;
#pragma unroll
    for (int i = 0; i < 4; ++i) {
        int n = base + tr * 4 + i;
        if (n < N_NODES) {
            ushort4 ov;
            ov.x = f2bf(acc[i][0]); ov.y = f2bf(acc[i][1]);
            ov.z = f2bf(acc[i][2]); ov.w = f2bf(acc[i][3]);
            *(ushort4*)(outB + (size_t)n * 64 + j0) = ov;
        }
    }
    {   // es2/ed2 epilogue
        float s0[4], s1[4];
#pragma unroll
        for (int i = 0; i < 4; ++i) {
            float pes = 0.f, ped = 0.f;
#pragma unroll
            for (int q = 0; q < 4; ++q) {
                pes = fmaf(acc[i][q], as2[j0 + q], pes);
                ped = fmaf(acc[i][q], ad2[j0 + q], ped);
            }
            pes += __shfl_xor(pes, 1, 64);
            ped += __shfl_xor(ped, 1, 64);
            s0[i] = pes; s1[i] = ped;
        }
        if ((tc & 1) == 0) {
            int h = tc >> 1;
#pragma unroll
            for (int i = 0; i < 4; ++i) {
                int n = base + tr * 4 + i;
                if (n < N_NODES) {
                    es2[n * NH + h] = s0[i];
                    ed2[n * NH + h] = s1[i];
                }
            }
        }
    }
}

// ---------------------------------------------------------------------------
// FUSED B: GAT2 aggregate -> B2 global (bf16) + LDS rows (fp32) -> dual proj
// (P1,P2) -> node attention.  smem: Ws[8192] | rows[64*68] = 49 KB.
// ---------------------------------------------------------------------------
__global__ __launch_bounds__(256)
void agg2_proj(const int* __restrict__ offs, const int* __restrict__ csr,
               const float* __restrict__ es2, const float* __restrict__ ed2,
               const bfu* __restrict__ BH1, const float* __restrict__ b2,
               bfu* __restrict__ B2,
               const float* __restrict__ ea_w1,
               bfu* __restrict__ P1, bfu* __restrict__ P2,
               const float* __restrict__ na_w1, const float* __restrict__ na_b1,
               const float* __restrict__ na_w2, const float* __restrict__ na_b2,
               float2* __restrict__ al2)
{
    __shared__ __align__(16) float smem[12544];
    float* Ws   = smem;            // 8192 floats
    float* rows = smem + 8192;     // 64*68
    int t = threadIdx.x;
    int base = blockIdx.x * 64;
    {   // stage ea_w1 halves early
        const float4* W0v = (const float4*)ea_w1;
        const float4* W1v = (const float4*)(ea_w1 + 64 * 64);
        float4* Wsv = (float4*)Ws;
        for (int i = t; i < 1024; i += 256) { Wsv[i] = W0v[i]; Wsv[1024 + i] = W1v[i]; }
    }
    agg_phase<0, 1>(rows, base, offs, csr, es2, ed2, BH1, b2, B2);
    __syncthreads();
    {   // ---- dual gemm from rows ----
        int tr = t >> 4, tc = t & 15;
        float a0[4][4] = {}, a1[4][4] = {};
        const float4* Wsv = (const float4*)Ws;
        const float4* R4 = (const float4*)rows;       // stride 17 float4s
#pragma unroll 2
        for (int k = 0; k < 64; k += 4) {
            float4 p0 = Wsv[(k + 0) * 16 + tc];
            float4 p1 = Wsv[(k + 1) * 16 + tc];
            float4 p2 = Wsv[(k + 2) * 16 + tc];
            float4 p3 = Wsv[(k + 3) * 16 + tc];
            float4 q0 = Wsv[1024 + (k + 0) * 16 + tc];
            float4 q1 = Wsv[1024 + (k + 1) * 16 + tc];
            float4 q2 = Wsv[1024 + (k + 2) * 16 + tc];
            float4 q3 = Wsv[1024 + (k + 3) * 16 + tc];
            int kq = k >> 2;
#pragma unroll
            for (int i = 0; i < 4; ++i) {
                float4 r = R4[(tr * 4 + i) * 17 + kq];
                a0[i][0] = fmaf(r.x, p0.x, fmaf(r.y, p1.x, fmaf(r.z, p2.x, fmaf(r.w, p3.x, a0[i][0]))));
                a0[i][1] = fmaf(r.x, p0.y, fmaf(r.y, p1.y, fmaf(r.z, p2.y, fmaf(r.w, p3.y, a0[i][1]))));
                a0[i][2] = fmaf(r.x, p0.z, fmaf(r.y, p1.z, fmaf(r.z, p2.z, fmaf(r.w, p3.z, a0[i][2]))));
                a0[i][3] = fmaf(r.x, p0.w, fmaf(r.y, p1.w, fmaf(r.z, p2.w, fmaf(r.w, p3.w, a0[i][3]))));
                a1[i][0] = fmaf(r.x, q0.x, fmaf(r.y, q1.x, fmaf(r.z, q2.x, fmaf(r.w, q3.x, a1[i][0]))));
                a1[i][1] = fmaf(r.x, q0.y, fmaf(r.y, q1.y, fmaf(r.z, q2.y, fmaf(r.w, q3.y, a1[i][1]))));
                a1[i][2] = fmaf(r.x, q0.z, fmaf(r.y, q1.z, fmaf(r.z, q2.z, fmaf(r.w, q3.z, a1[i][2]))));
                a1[i][3] = fmaf(r.x, q0.w, fmaf(r.y, q1.w, fmaf(r.z, q2.w, fmaf(r.w, q3.w, a1[i][3]))));
            }
        }
        int j0 = tc * 4;
#pragma unroll
        for (int i = 0; i < 4; ++i) {
            int n = base + tr * 4 + i;
            if (n >= N_NODES) continue;
            ushort4 o0, o1;
            o0.x = f2bf(a0[i][0]); o0.y = f2bf(a0[i][1]);
            o0.z = f2bf(a0[i][2]); o0.w = f2bf(a0[i][3]);
            o1.x = f2bf(a1[i][0]); o1.y = f2bf(a1[i][1]);
            o1.z = f2bf(a1[i][2]); o1.w = f2bf(a1[i][3]);
            *(ushort4*)(P1 + (size_t)n * 64 + j0) = o0;
            *(ushort4*)(P2 + (size_t)n * 64 + j0) = o1;
        }
    }
    // ---- node attention from the SAME rows tile ----
    __syncthreads();                 // everyone done reading Ws
    {
        const float4* w1v = (const float4*)na_w1;
        float4* dst = (float4*)Ws;
        for (int i = t; i < 512; i += 256) dst[i] = w1v[i];
        if (t < 64) Ws[2048 + t] = na_w2[t];
    }
    __syncthreads();
    {
        int tr = t >> 3;
        int tc = t & 7;
        float4 bv = *(const float4*)(na_b1 + tc * 4);
        float4 acc0 = bv, acc1 = bv;
        const float4* w1sv = (const float4*)Ws;
#pragma unroll 8
        for (int k = 0; k < 64; ++k) {
            float4 w = w1sv[k * 8 + tc];
            float r0 = rows[tr * 68 + k];
            float r1 = rows[(tr + 32) * 68 + k];
            acc0.x = fmaf(r0, w.x, acc0.x); acc0.y = fmaf(r0, w.y, acc0.y);
            acc0.z = fmaf(r0, w.z, acc0.z); acc0.w = fmaf(r0, w.w, acc0.w);
            acc1.x = fmaf(r1, w.x, acc1.x); acc1.y = fmaf(r1, w.y, acc1.y);
            acc1.z = fmaf(r1, w.z, acc1.z); acc1.w = fmaf(r1, w.w, acc1.w);
        }
        float z00 = 0.f, z01 = 0.f, z10 = 0.f, z11 = 0.f;
        float h0, w20, w21;
        int j0 = tc * 4;
#pragma unroll
        for (int q = 0; q < 4; ++q) {
            float a0q = q == 0 ? acc0.x : q == 1 ? acc0.y : q == 2 ? acc0.z : acc0.w;
            float a1q = q == 0 ? acc1.x : q == 1 ? acc1.y : q == 2 ? acc1.z : acc1.w;
            w20 = Ws[2048 + (j0 + q) * 2]; w21 = Ws[2048 + (j0 + q) * 2 + 1];
            h0 = fmaxf(a0q, 0.f);
            z00 = fmaf(h0, w20, z00); z01 = fmaf(h0, w21, z01);
            h0 = fmaxf(a1q, 0.f);
            z10 = fmaf(h0, w20, z10); z11 = fmaf(h0, w21, z11);
        }
#pragma unroll
        for (int o = 1; o < 8; o <<= 1) {
            z00 += __shfl_xor(z00, o, 64); z01 += __shfl_xor(z01, o, 64);
            z10 += __shfl_xor(z10, o, 64); z11 += __shfl_xor(z11, o, 64);
        }
        if (tc == 0) {
            int n0 = base + tr, n1 = base + tr + 32;
            if (n0 < N_NODES) {
                float zz0 = z00 + na_b2[0], zz1 = z01 + na_b2[1];
                float mx = fmaxf(zz0, zz1);
                float e0 = __expf(zz0 - mx), e1 = __expf(zz1 - mx);
                float ss = e0 + e1;
                al2[n0] = make_float2(e0 / ss, e1 / ss);
            }
            if (n1 < N_NODES) {
                float zz0 = z10 + na_b2[0], zz1 = z11 + na_b2[1];
                float mx = fmaxf(zz0, zz1);
                float e0 = __expf(zz0 - mx), e1 = __expf(zz1 - mx);
                float ss = e0 + e1;
                al2[n1] = make_float2(e0 / ss, e1 / ss);
            }
        }
    }
}

// ---------------------------------------------------------------------------
// weight prep body: Wp = gw @ rw (64x64), bp = gb @ rw + rb.  smem: 8192 floats
// ---------------------------------------------------------------------------
__device__ __forceinline__
void weight_prep_body(float* smem,
                      const float* __restrict__ gw, const float* __restrict__ gb,
                      const float* __restrict__ rw, const float* __restrict__ rb,
                      float* __restrict__ Wp, float* __restrict__ bp)
{
    float* A = smem;           // 4096
    float* B = smem + 4096;    // 4096
    int t = threadIdx.x;
    {
        const float4* ga = (const float4*)gw;
        const float4* rA = (const float4*)rw;
        float4* dA = (float4*)A; float4* dB = (float4*)B;
        for (int i = t; i < 1024; i += 256) { dA[i] = ga[i]; dB[i] = rA[i]; }
    }
    __syncthreads();
    for (int e = t * 16; e < t * 16 + 16; ++e) {
        int k = e >> 6, j = e & 63;
        float acc = 0.f;
#pragma unroll 8
        for (int m = 0; m < 64; ++m) acc = fmaf(A[k * 64 + m], B[m * 64 + j], acc);
        Wp[e] = acc;
    }
    if (t < 64) {
        float acc = rb[t];
#pragma unroll 8
        for (int m = 0; m < 64; ++m) acc = fmaf(gb[m], B[m * 64 + t], acc);
        bp[t] = acc;
    }
}

// ---------------------------------------------------------------------------
// UNION 1: weight_prep x2  ∪  gemm1 tiles [0,T1)  ∪  hist+rank (2-wide unroll)
// ---------------------------------------------------------------------------
__global__ __launch_bounds__(256)
void u1_fused(const float* __restrict__ x, const float* __restrict__ W1,
              bfu* __restrict__ B0, const float* __restrict__ as1,
              const float* __restrict__ ad1, float* __restrict__ es,
              float* __restrict__ ed,
              const int* __restrict__ ei, int* __restrict__ cnt,
              int* __restrict__ rank,
              const float* __restrict__ gc_w, const float* __restrict__ gc_b,
              const float* __restrict__ rc_w, const float* __restrict__ rc_b,
              const float* __restrict__ gt_w, const float* __restrict__ gt_b,
              const float* __restrict__ rt_w, const float* __restrict__ rt_b,
              float* __restrict__ Wcp, float* __restrict__ bcp,
              float* __restrict__ Wtp, float* __restrict__ btp)
{
    __shared__ __align__(16) float smem[12544];
    int b = blockIdx.x;
    if (b < 2) {
        if (b == 0) weight_prep_body(smem, gc_w, gc_b, rc_w, rc_b, Wcp, bcp);
        else        weight_prep_body(smem, gt_w, gt_b, rt_w, rt_b, Wtp, btp);
        return;
    }
    int u = b - 2;
    int stripe = u / 7, r = u % 7;
    if (r < 3) {
        gemm_tile_body<float, FIN, 1>(smem, stripe * 3 + r, x, W1, B0, as1, ad1, es, ed);
    } else {
        int idx = stripe * 4 + (r - 3);
        int t = threadIdx.x;
        const int STR = U1_HISTB * 256;
        for (int e = idx * 256 + t; e < E_EDGES; e += 2 * STR) {
            int e1 = e + STR;
            int d0 = ei[E_EDGES + e];
            int r0 = atomicAdd(&cnt[d0], 1);
            int r1 = 0;
            bool has1 = e1 < E_EDGES;
            if (has1) r1 = atomicAdd(&cnt[ei[E_EDGES + e1]], 1);
            rank[e] = r0;
            if (has1) rank[e1] = r1;
        }
    }
}

// ---------------------------------------------------------------------------
// UNION 2: atomic-free scatter  ∪  gemm1 tiles [T1,NBLK64)  ∪  self-slot mark
// ---------------------------------------------------------------------------
__global__ __launch_bounds__(256)
void u2_fused(const float* __restrict__ x, const float* __restrict__ W1,
              bfu* __restrict__ B0, const float* __restrict__ as1,
              const float* __restrict__ ad1, float* __restrict__ es,
              float* __restrict__ ed,
              const int* __restrict__ ei, const int* __restrict__ rank,
              const int* __restrict__ offs,
              int* __restrict__ csr)
{
    __shared__ __align__(16) float smem[12544];
    int b = blockIdx.x;
    int stripe = b / 11, r = b % 11;
    int t = threadIdx.x;
    if (r < 8) {
        int e = (stripe * 8 + r) * 256 + t;
        if (e < E_EDGES) {
            int s = ei[e], d = ei[E_EDGES + e];
            csr[offs[d] + rank[e]] = s;
        }
    } else if (r < 10) {
        int tile = T1 + stripe * 2 + (r - 8);
        if (tile < NBLK64)
            gemm_tile_body<float, FIN, 1>(smem, tile, x, W1, B0, as1, ad1, es, ed);
    } else {
        int n = stripe * 256 + t;
        if (n < N_NODES) {
            csr[offs[n + 1] - 1] = n | SELF_FLAG;  // self loop ALWAYS last slot
        }
    }
}

// ---------------------------------------------------------------------------
// CSR scan chain: scan1 (local scans + raw block sums + graph boundaries),
// scan23 (each block recomputes its bsum prefix; no serial pass)
// ---------------------------------------------------------------------------
__global__ void csr_scan1(const int* __restrict__ cnt, int* __restrict__ offs,
                          int* __restrict__ bsum, const int* __restrict__ batch,
                          int* __restrict__ glo)
{
    __shared__ int tmp[256];
    int t = threadIdx.x;
    int i = blockIdx.x * 256 + t;
    int v = (i < N_NODES) ? cnt[i] + 1 : 0;
    tmp[t] = v; __syncthreads();
#pragma unroll
    for (int o = 1; o < 256; o <<= 1) {
        int a = (t >= o) ? tmp[t - o] : 0;
        __syncthreads();
        tmp[t] += a;
        __syncthreads();
    }
    if (i < N_NODES) offs[i] = tmp[t] - v;
    if (t == 255) bsum[blockIdx.x] = tmp[255];
    // graph boundaries: glo[g] = lower_bound(batch, g), g = 0..NG
    if (blockIdx.x == 0 && t <= NG) {
        int l = 0, r = N_NODES;
        while (l < r) { int m = (l + r) >> 1; if (batch[m] < t) l = m + 1; else r = m; }
        glo[t] = l;
    }
}

__global__ void csr_scan23(int* __restrict__ offs, const int* __restrict__ bsum)
{
    __shared__ int tmp[256];
    int b = blockIdx.x;
    int t = threadIdx.x;
    int s = 0;
    for (int j = t; j < b; j += 256) s += bsum[j];
    tmp[t] = s; __syncthreads();
#pragma unroll
    for (int o = 128; o > 0; o >>= 1) {
        if (t < o) tmp[t] += tmp[t + o];
        __syncthreads();
    }
    int prefix = tmp[0];
    int i = b * 256 + t;
    if (i < N_NODES) offs[i] += prefix;
    if (i == 0) offs[N_NODES] = E2;
}

// ---------------------------------------------------------------------------
// edge attention, per-NODE, NPW nodes per wave (setup amortized): 8 edge-slots
// x 8 feature-lanes.  Wave-invariant weights/biases loaded ONCE per wave; the
// wave then walks NPW consecutive nodes.  Pass 1 stages beta in per-wave LDS.
// Pass 2 writes scaled {beta*dis[d]} coalesced, incl. self slot.
// prod2[n] = {dis*alpha}.  Overflow (deg>ECAP) falls back to global staging.
// ---------------------------------------------------------------------------
__global__ __launch_bounds__(256)
void edge_att_node(const int* __restrict__ offs, const int* __restrict__ csr,
                   const bfu* __restrict__ P1b, const bfu* __restrict__ P2b,
                   const float* __restrict__ b1, const float* __restrict__ w2,
                   const float* __restrict__ b2,
                   const float2* __restrict__ al2,
                   float2* __restrict__ beta2,
                   float2* __restrict__ prod2)
{
    __shared__ float2 bbuf[4][ECAP];             // 8 KB: per-wave beta staging
    int w = threadIdx.x >> 6;                    // wave id in block
    int lane = threadIdx.x & 63;
    int nbase = (blockIdx.x * 4 + w) * NPW;
    if (nbase >= N_NODES) return;
    int slot = lane >> 3, q = lane & 7;
    // ---- wave-invariant setup (once) ----
    const float4* pb = (const float4*)(b1 + q * 8);
    const float4* pw = (const float4*)(w2 + q * 16);
    float4 c0 = pb[0], c1 = pb[1];
    float4 w0 = pw[0], w1v = pw[1], w2v = pw[2], w3v = pw[3];
    float wd0 = w0.x - w0.y,   wd1 = w0.z - w0.w;
    float wd2 = w1v.x - w1v.y, wd3 = w1v.z - w1v.w;
    float wd4 = w2v.x - w2v.y, wd5 = w2v.z - w2v.w;
    float wd6 = w3v.x - w3v.y, wd7 = w3v.z - w3v.w;
    float zbd = b2[0] - b2[1];
    for (int j = 0; j < NPW; ++j) {
        int n = nbase + j;
        if (n >= N_NODES) return;
        uint4 U2 = *(const uint4*)(P2b + (size_t)n * 64 + q * 8);
        float d0 = bflo(U2.x) + c0.x, d1 = bfhi(U2.x) + c0.y;
        float d2 = bflo(U2.y) + c0.z, d3 = bfhi(U2.y) + c0.w;
        float d4 = bflo(U2.z) + c1.x, d5 = bfhi(U2.z) + c1.y;
        float d6 = bflo(U2.w) + c1.z, d7 = bfhi(U2.w) + c1.w;
        int beg = offs[n], endr = offs[n + 1] - 1;   // real edges only
        int m = endr - beg;
        float dc = 0.f, dt = 0.f;
        for (int p = beg + slot; p < endr; p += 8) {
            int s = csr[p];                           // real edge: raw src index
            uint4 U1 = *(const uint4*)(P1b + (size_t)s * 64 + q * 8);
            float h0 = fmaxf(bflo(U1.x) + d0, 0.f);
            float h1 = fmaxf(bfhi(U1.x) + d1, 0.f);
            float h2 = fmaxf(bflo(U1.y) + d2, 0.f);
            float h3 = fmaxf(bfhi(U1.y) + d3, 0.f);
            float h4 = fmaxf(bflo(U1.z) + d4, 0.f);
            float h5 = fmaxf(bfhi(U1.z) + d5, 0.f);
            float h6 = fmaxf(bflo(U1.w) + d6, 0.f);
            float h7 = fmaxf(bfhi(U1.w) + d7, 0.f);
            float z = fmaf(h0, wd0, fmaf(h1, wd1, fmaf(h2, wd2, fmaf(h3, wd3,
                      fmaf(h4, wd4, fmaf(h5, wd5, fmaf(h6, wd6, h7 * wd7)))))));
            z += __shfl_xor(z, 1, 64);
            z += __shfl_xor(z, 2, 64);
            z += __shfl_xor(z, 4, 64);
            if (q == 0) {
                z += zbd;
                // beta_c = sigmoid(z), beta_t = sigmoid(-z), numerically stable
                float e = __expf(-fabsf(z));
                float inv = 1.f / (1.f + e);
                float bx = z >= 0.f ? inv : e * inv;
                float by = z >= 0.f ? e * inv : inv;
                int idx = p - beg;
                if (idx < ECAP) bbuf[w][idx] = make_float2(bx, by);
                else            beta2[p]    = make_float2(bx, by);  // rare
                dc += bx; dt += by;
            }
        }
        // reduce across the 8 slots (only q==0 lanes hold nonzero partials)
        dc += __shfl_xor(dc, 8, 64);  dt += __shfl_xor(dt, 8, 64);
        dc += __shfl_xor(dc, 16, 64); dt += __shfl_xor(dt, 16, 64);
        dc += __shfl_xor(dc, 32, 64); dt += __shfl_xor(dt, 32, 64);
        dc = __shfl(dc, 0, 64); dt = __shfl(dt, 0, 64);
        dc += 1.f; dt += 1.f;                         // self loop contribution
        float ic = rsqrtf(fmaxf(dc, 1e-20f));
        float it = rsqrtf(fmaxf(dt, 1e-20f));
        if (lane == 0) {
            float2 al = al2[n];
            prod2[n] = make_float2(ic * al.x, it * al.y);
        }
        if (m > ECAP)                                 // order overflow stores
            asm volatile("s_waitcnt vmcnt(0)" ::: "memory");
        // pass 2: coalesced scaled stores; idx==m is the self slot ({ic,it})
        for (int idx = lane; idx <= m; idx += 64) {
            float2 v = (idx == m) ? make_float2(1.f, 1.f)
                     : (idx < ECAP) ? bbuf[w][idx] : beta2[beg + idx];
            beta2[beg + idx] = make_float2(v.x * ic, v.y * it);
        }
    }
}

// ---------------------------------------------------------------------------
// FUSED GCN aggregate + graph readout:
// w_c = prod_c[s] * beta2_c[p]   (beta2 already contains beta*dis[d]; self
// slots contain dis[d]).  No csrd, no dis2, no flag select.
// ---------------------------------------------------------------------------
__global__ __launch_bounds__(256)
void gcn_readout_fused(const int* __restrict__ offs, const int* __restrict__ csr,
                       const int* __restrict__ glo,
                       const bfu* __restrict__ HB,
                       const float2* __restrict__ beta2,
                       const float2* __restrict__ prod2,
                       float* __restrict__ Pc, float* __restrict__ Pt)
{
    int g = blockIdx.x / GB, b = blockIdx.x % GB;
    int t = threadIdx.x;
    int pbeg = offs[glo[g]], pend = offs[glo[g + 1]];
    int total = pend - pbeg;
    int chunk = (total + GB - 1) / GB;
    int start = pbeg + b * chunk;
    int end = start + chunk;
    if (end > pend) end = pend;
    if (start > pend) start = pend;
    int slot = t >> 4, fl = t & 15;
    float4 a1 = make_float4(0.f, 0.f, 0.f, 0.f);
    float4 a2 = make_float4(0.f, 0.f, 0.f, 0.f);
    int p = start + slot;
    for (; p + 48 < end; p += 64) {
#pragma unroll
        for (int j = 0; j < 4; ++j) {
            int pp = p + j * 16;
            int s = csr[pp] & SRC_MASK;
            float2 bb = beta2[pp];
            float2 pr = prod2[s];
            float wc = pr.x * bb.x;
            float wt = pr.y * bb.y;
            ushort4 r0 = *(const ushort4*)(HB + (size_t)s * HD + fl * 4);
            float f0 = bf2f(r0.x), f1 = bf2f(r0.y), f2 = bf2f(r0.z), f3 = bf2f(r0.w);
            a1.x = fmaf(f0, wc, a1.x); a1.y = fmaf(f1, wc, a1.y);
            a1.z = fmaf(f2, wc, a1.z); a1.w = fmaf(f3, wc, a1.w);
            a2.x = fmaf(f0, wt, a2.x); a2.y = fmaf(f1, wt, a2.y);
            a2.z = fmaf(f2, wt, a2.z); a2.w = fmaf(f3, wt, a2.w);
        }
    }
    for (; p < end; p += 16) {
        int s = csr[p] & SRC_MASK;
        float2 bb = beta2[p];
        float2 pr = prod2[s];
        float wc = pr.x * bb.x;
        float wt = pr.y * bb.y;
        ushort4 r0 = *(const ushort4*)(HB + (size_t)s * HD + fl * 4);
        float f0 = bf2f(r0.x), f1 = bf2f(r0.y), f2 = bf2f(r0.z), f3 = bf2f(r0.w);
        a1.x = fmaf(f0, wc, a1.x); a1.y = fmaf(f1, wc, a1.y);
        a1.z = fmaf(f2, wc, a1.z); a1.w = fmaf(f3, wc, a1.w);
        a2.x = fmaf(f0, wt, a2.x); a2.y = fmaf(f1, wt, a2.y);
        a2.z = fmaf(f2, wt, a2.z); a2.w = fmaf(f3, wt, a2.w);
    }
    __shared__ float redc[16 * 64], redt[16 * 64];
    *(float4*)(redc + slot * 64 + fl * 4) = a1;
    *(float4*)(redt + slot * 64 + fl * 4) = a2;
    __syncthreads();
    if (t < 64) {
        float sc = 0.f, st = 0.f;
#pragma unroll
        for (int s = 0; s < 16; ++s) { sc += redc[s * 64 + t]; st += redt[s * 64 + t]; }
        Pc[(size_t)blockIdx.x * 64 + t] = sc;
        Pt[(size_t)blockIdx.x * 64 + t] = st;
    }
}

// ---------------------------------------------------------------------------
// final heads: one 64-thread block per graph.
// ---------------------------------------------------------------------------
__global__ __launch_bounds__(64)
void head_final(const float* __restrict__ Pc, const float* __restrict__ Pt,
                const int* __restrict__ glo,
                const float* __restrict__ Wcp, const float* __restrict__ bcp,
                const float* __restrict__ Wtp, const float* __restrict__ btp,
                const float* __restrict__ cc_w1, const float* __restrict__ cc_b1,
                const float* __restrict__ cc_w2, const float* __restrict__ cc_b2,
                const float* __restrict__ ct_w1, const float* __restrict__ ct_b1,
                const float* __restrict__ ct_w2, const float* __restrict__ ct_b2,
                const float* __restrict__ cm_w1, const float* __restrict__ cm_b1,
                const float* __restrict__ cm_w2, const float* __restrict__ cm_b2,
                float* __restrict__ out)
{
    int g = blockIdx.x;
    int t = threadIdx.x;
    __shared__ float scl[64], stl[64], hgc[64], hgt[64], hid[64];
    float sc = 0.f, st = 0.f;
#pragma unroll
    for (int b = 0; b < GB; ++b) {
        sc += Pc[(size_t)(g * GB + b) * 64 + t];
        st += Pt[(size_t)(g * GB + b) * 64 + t];
    }
    scl[t] = sc; stl[t] = st;
    float c = (float)(glo[g + 1] - glo[g]);
    __syncthreads();
    {
        float a = c * bcp[t], bb = c * btp[t];
#pragma unroll 8
        for (int k = 0; k < 64; ++k) {
            a  = fmaf(scl[k], Wcp[k * 64 + t], a);
            bb = fmaf(stl[k], Wtp[k * 64 + t], bb);
        }
        hgc[t] = a; hgt[t] = bb;
        out[3840 + g * 64 + t]  = a;
        out[12032 + g * 64 + t] = bb;
    }
    __syncthreads();
    if (t < 32) {
        float a = cc_b1[t];
#pragma unroll 8
        for (int k = 0; k < 64; ++k) a = fmaf(hgc[k], cc_w1[k * 32 + t], a);
        hid[t] = fmaxf(a, 0.f);
    }
    __syncthreads();
    if (t < NC) {
        float a = cc_b2[t];
#pragma unroll
        for (int k = 0; k < 32; ++k) a = fmaf(hid[k], cc_w2[k * NC + t], a);
        out[g * NC + t] = a;
    }
    __syncthreads();
    if (t < 32) {
        float a = ct_b1[t];
#pragma unroll 8
        for (int k = 0; k < 64; ++k) a = fmaf(hgt[k], ct_w1[k * 32 + t], a);
        hid[t] = fmaxf(a, 0.f);
    }
    __syncthreads();
    if (t < NC) {
        float a = ct_b2[t];
#pragma unroll
        for (int k = 0; k < 32; ++k) a = fmaf(hid[k], ct_w2[k * NC + t], a);
        out[1280 + g * NC + t] = a;
    }
    __syncthreads();
    {
        float a = cm_b1[t];
#pragma unroll 8
        for (int k = 0; k < 64; ++k) {
            a = fmaf(hgc[k], cm_w1[k * 64 + t], a);
            a = fmaf(hgt[k], cm_w1[(64 + k) * 64 + t], a);
        }
        hid[t] = fmaxf(a, 0.f);
    }
    __syncthreads();
    if (t < NC) {
        float a = cm_b2[t];
#pragma unroll 8
        for (int k = 0; k < 64; ++k) a = fmaf(hid[k], cm_w2[k * NC + t], a);
        out[2560 + g * NC + t] = a;
    }
}

// ---------------------------------------------------------------------------
extern "C" void kernel_launch(void* const* d_in, const int* in_sizes, int n_in,
                              void* d_out, int out_size, void* d_ws, size_t ws_size,
                              hipStream_t stream)
{
    const float* x     = (const float*)d_in[0];
    const int*   ei    = (const int*)d_in[1];
    const int*   batch = (const int*)d_in[2];
    const float* W1    = (const float*)d_in[3];
    const float* as1   = (const float*)d_in[4];
    const float* ad1   = (const float*)d_in[5];
    const float* b1    = (const float*)d_in[6];
    const float* W2    = (const float*)d_in[7];
    const float* as2   = (const float*)d_in[8];
    const float* ad2   = (const float*)d_in[9];
    const float* b2    = (const float*)d_in[10];
    const float* na_w1 = (const float*)d_in[11];
    const float* na_b1 = (const float*)d_in[12];
    const float* na_w2 = (const float*)d_in[13];
    const float* na_b2 = (const float*)d_in[14];
    const float* ea_w1 = (const float*)d_in[15];
    const float* ea_b1 = (const float*)d_in[16];
    const float* ea_w2 = (const float*)d_in[17];
    const float* ea_b2 = (const float*)d_in[18];
    const float* gc_w  = (const float*)d_in[19];
    const float* gc_b  = (const float*)d_in[20];
    const float* gt_w  = (const float*)d_in[21];
    const float* gt_b  = (const float*)d_in[22];
    const float* rc_w  = (const float*)d_in[23];
    const float* rc_b  = (const float*)d_in[24];
    const float* rt_w  = (const float*)d_in[25];
    const float* rt_b  = (const float*)d_in[26];
    const float* cc_w1 = (const float*)d_in[27];
    const float* cc_b1 = (const float*)d_in[28];
    const float* cc_w2 = (const float*)d_in[29];
    const float* cc_b2 = (const float*)d_in[30];
    const float* ct_w1 = (const float*)d_in[31];
    const float* ct_b1 = (const float*)d_in[32];
    const float* ct_w2 = (const float*)d_in[33];
    const float* ct_b2 = (const float*)d_in[34];
    const float* cm_w1 = (const float*)d_in[35];
    const float* cm_b1 = (const float*)d_in[36];
    const float* cm_w2 = (const float*)d_in[37];
    const float* cm_b2 = (const float*)d_in[38];
    float* out = (float*)d_out;

    float* ws = (float*)d_ws;
    size_t o = 0;
    const size_t nf = (size_t)N_NODES * HD;
    float* es    = ws + o; o += (size_t)N_NODES * NH;
    float* ed    = ws + o; o += (size_t)N_NODES * NH;
    float2* al2  = (float2*)(ws + o); o += (size_t)N_NODES * 2;
    float2* beta2= (float2*)(ws + o); o += (size_t)E2 * 2;      // {beta_c,beta_t}*dis[d]
    float2* prod2= (float2*)(ws + o); o += (size_t)N_NODES * 2; // {dis*alpha} per node
    bfu* B0      = (bfu*)(ws + o); o += nf / 2; // GAT1 transform -> later P1
    bfu* B1      = (bfu*)(ws + o); o += nf / 2; // rank -> P2
    bfu* B2      = (bfu*)(ws + o); o += nf / 2; // H table (bf16)
    bfu* BH1     = (bfu*)(ws + o); o += nf / 2; // GAT2 transform table
    int* csr     = (int*)(ws + o); o += E2;
    int* offs    = (int*)(ws + o); o += N_NODES + 1;
    float* Pc    = ws + o; o += (size_t)NG * GB * 64;
    float* Pt    = ws + o; o += (size_t)NG * GB * 64;
    float* Wcp   = ws + o; o += 4096;
    float* Wtp   = ws + o; o += 4096;
    float* bcp   = ws + o; o += 64;
    float* btp   = ws + o; o += 64;
    int* glo     = (int*)(ws + o); o += NG + 2;  // graph node boundaries
    // temporaries alias buffers written later:
    int* cnt  = (int*)beta2;   // used in U1+scan1; region reused below, then beta2
    int* bsum = (int*)prod2;   // used in scans; prod2 written by edge_att later
    int* rank = (int*)B1;      // written U1, read U2; B1 written in agg2_proj later
    // GAT2 es/ed: alias the beta2 region (cnt dead after scan1; beta2 written
    // by edge_att AFTER agg2_proj consumed es2/ed2).  2*N*NH = 1.6M <= E2*2.
    float* es2 = (float*)beta2;
    float* ed2 = es2 + (size_t)N_NODES * NH;

    // ---------------- CSR count + GAT1 gemm (first chunk) + weight prep -----
    hipMemsetAsync(cnt, 0, (size_t)N_NODES * 4, stream);
    u1_fused<<<U1_GRID, 256, 0, stream>>>(x, W1, B0, as1, ad1, es, ed,
                                          ei, cnt, rank,
                                          gc_w, gc_b, rc_w, rc_b,
                                          gt_w, gt_b, rt_w, rt_b,
                                          Wcp, bcp, Wtp, btp);
    csr_scan1<<<NSCAN_BLK, 256, 0, stream>>>(cnt, offs, bsum, batch, glo);
    csr_scan23<<<NSCAN_BLK, 256, 0, stream>>>(offs, bsum);

    // ---------------- scatter (atomic-free) + self mark + GAT1 gemm (rest) --
    u2_fused<<<U2_GRID, 256, 0, stream>>>(x, W1, B0, as1, ad1, es, ed,
                                          ei, rank, offs, csr);

    // ---------------- FUSED: GAT1 aggregate -> GAT2 gemm (H1 stays in LDS) --
    agg1_gemm2<<<NBLK64, 256, 0, stream>>>(offs, csr, es, ed, B0, b1,
                                           W2, BH1, as2, ad2, es2, ed2);

    // ---------------- FUSED: GAT2 aggregate -> dual proj + node att ---------
    agg2_proj<<<NBLK64, 256, 0, stream>>>(offs, csr, es2, ed2, BH1, b2,
                                          B2, ea_w1, B0, B1,
                                          na_w1, na_b1, na_w2, na_b2, al2);

    // ---------------- edge attention + degree + LDS-staged dis[d] fold ------
    edge_att_node<<<EA_BLKS, 256, 0, stream>>>(offs, csr, B0, B1,
                                               ea_b1, ea_w2, ea_b2, al2,
                                               beta2, prod2);

    // ---------------- fused GCN aggregate + readout -------------------------
    gcn_readout_fused<<<NG * GB, 256, 0, stream>>>(offs, csr, glo, B2,
                                                   beta2, prod2, Pc, Pt);

    // ---------------- final heads -------------------------------------------
    head_final<<<NG, 64, 0, stream>>>(Pc, Pt, glo,
                                      Wcp, bcp, Wtp, btp,
                                      cc_w1, cc_b1, cc_w2, cc_b2,
                                      ct_w1, ct_b1, ct_w2, ct_b2,
                                      cm_w1, cm_b1, cm_w2, cm_b2, out);
    (void)in_sizes; (void)n_in; (void)out_size; (void)ws_size;
}

// Round 10
// 442.916 us; speedup vs baseline: 1.0839x; 1.0839x over previous
//
#include <hip/hip_runtime.h>
#include <hip/hip_bf16.h>

#define N_NODES 100000
#define E_EDGES 800000
#define E2 (E_EDGES + N_NODES)   // 900000 edges incl. self loops
#define FIN 128
#define HD 64
#define NH 8
#define NG 128
#define NC 10
#define SLOPE 0.2f
#define SELF_FLAG 0x40000000
#define SRC_MASK  0x3FFFFFFF
#define NSCAN_BLK 391            // ceil(N/256)
#define NBLK64 1563              // ceil(N/64)
#define GB 16                    // blocks per graph in fused gcn+readout
#define ECAP 256                 // LDS beta slots per node in edge_att
#define NPW 8                    // nodes per wave in edge_att
#define EA_BLKS 3125             // N / (4 waves * NPW)
#define AG_BLKS 6250             // N / (4 waves * 4 nodes-per-wave)

// union-kernel geometry
#define U1_STRIPES 261
#define U1_GRID (2 + U1_STRIPES * 7)     // 1829: 2 wprep + 783 gemm + 1044 hist
#define U1_HISTB (U1_STRIPES * 4)        // 1044
#define T1 (U1_STRIPES * 3)              // 783 gemm tiles in U1
#define U2_STRIPES 391
#define U2_GRID (U2_STRIPES * 11)        // 4301: 3128 scatter + 782 gemm + 391 selfmark

typedef unsigned short bfu;

__device__ __forceinline__ float lrelu(float x) { return x > 0.f ? x : SLOPE * x; }

__device__ __forceinline__ bfu f2bf(float f) {
    unsigned int u = __float_as_uint(f);
    u += 0x7FFFu + ((u >> 16) & 1u);          // round-to-nearest-even
    return (bfu)(u >> 16);
}
__device__ __forceinline__ float bf2f(bfu s) {
    return __uint_as_float(((unsigned int)s) << 16);
}
__device__ __forceinline__ float bflo(unsigned int u) { return __uint_as_float(u << 16); }
__device__ __forceinline__ float bfhi(unsigned int u) { return __uint_as_float(u & 0xFFFF0000u); }

// ---------------------------------------------------------------------------
// Tiled node GEMM body: 64 nodes/tile, thread = 4 nodes x 4 outputs.
// smem layout: Ws[KH*64] | rows[64*(KIN+4)]
// ---------------------------------------------------------------------------
template<typename TIN, int KIN, int MODE>
__device__ __forceinline__
void gemm_tile_body(float* smem, int tile,
                    const TIN* __restrict__ in, const float* __restrict__ W,
                    bfu* __restrict__ outB,
                    const float* __restrict__ a_s, const float* __restrict__ a_d,
                    float* __restrict__ es, float* __restrict__ ed)
{
    constexpr int KH = (KIN > 64) ? 64 : KIN;     // K chunk staged at once
    constexpr int RS = KIN + 4;                   // rows stride (floats), %4==0
    float* Ws   = smem;                           // KH*64
    float* rows = smem + KH * 64;                 // 64*RS
    int t = threadIdx.x;
    int base = tile * 64;

    // ---- stage input rows (fp32) ----
    if constexpr (sizeof(TIN) == 4) {
        constexpr int RQ = KIN / 4;
        for (int i = t; i < 64 * RQ; i += 256) {
            int r = i / RQ, c = (i % RQ) * 4;
            int n = base + r;
            float4 v = make_float4(0.f, 0.f, 0.f, 0.f);
            if (n < N_NODES) v = *(const float4*)((const float*)in + (size_t)n * KIN + c);
            *(float4*)(rows + r * RS + c) = v;
        }
    } else {
        constexpr int RQ = KIN / 8;
        for (int i = t; i < 64 * RQ; i += 256) {
            int r = i / RQ, c = (i % RQ) * 8;
            int n = base + r;
            uint4 v = make_uint4(0, 0, 0, 0);
            if (n < N_NODES) v = *(const uint4*)((const bfu*)in + (size_t)n * KIN + c);
            float* dp = rows + r * RS + c;
            *(float4*)dp       = make_float4(bflo(v.x), bfhi(v.x), bflo(v.y), bfhi(v.y));
            *(float4*)(dp + 4) = make_float4(bflo(v.z), bfhi(v.z), bflo(v.w), bfhi(v.w));
        }
    }

    int tr = t >> 4, tc = t & 15;
    float acc[4][4] = {};
    const float4* R4 = (const float4*)rows;       // stride RS/4 float4s

    for (int h = 0; h < KIN / KH; ++h) {
        __syncthreads();                          // rows ready (h=0) / Ws free (h>0)
        {
            const float4* Wv = (const float4*)(W + (size_t)h * KH * 64);
            float4* Wsv4 = (float4*)Ws;
            for (int i = t; i < KH * 16; i += 256) Wsv4[i] = Wv[i];
        }
        __syncthreads();
        const float4* Wsv = (const float4*)Ws;
#pragma unroll 2
        for (int k = 0; k < KH; k += 4) {
            float4 w0 = Wsv[(k + 0) * 16 + tc];
            float4 w1 = Wsv[(k + 1) * 16 + tc];
            float4 w2 = Wsv[(k + 2) * 16 + tc];
            float4 w3 = Wsv[(k + 3) * 16 + tc];
            int kq = (h * KH + k) >> 2;
#pragma unroll
            for (int i = 0; i < 4; ++i) {
                float4 r = R4[(tr * 4 + i) * (RS / 4) + kq];
                acc[i][0] = fmaf(r.x, w0.x, fmaf(r.y, w1.x, fmaf(r.z, w2.x, fmaf(r.w, w3.x, acc[i][0]))));
                acc[i][1] = fmaf(r.x, w0.y, fmaf(r.y, w1.y, fmaf(r.z, w2.y, fmaf(r.w, w3.y, acc[i][1]))));
                acc[i][2] = fmaf(r.x, w0.z, fmaf(r.y, w1.z, fmaf(r.z, w2.z, fmaf(r.w, w3.z, acc[i][2]))));
                acc[i][3] = fmaf(r.x, w0.w, fmaf(r.y, w1.w, fmaf(r.z, w2.w, fmaf(r.w, w3.w, acc[i][3]))));
            }
        }
    }

    int j0 = tc * 4;
#pragma unroll
    for (int i = 0; i < 4; ++i) {
        int n = base + tr * 4 + i;
        if (n < N_NODES) {
            ushort4 ov;
            ov.x = f2bf(acc[i][0]); ov.y = f2bf(acc[i][1]);
            ov.z = f2bf(acc[i][2]); ov.w = f2bf(acc[i][3]);
            *(ushort4*)(outB + (size_t)n * 64 + j0) = ov;
        }
    }
    if (MODE == 1) {
        float s0[4], s1[4];
#pragma unroll
        for (int i = 0; i < 4; ++i) {
            float pes = 0.f, ped = 0.f;
#pragma unroll
            for (int q = 0; q < 4; ++q) {
                pes = fmaf(acc[i][q], a_s[j0 + q], pes);
                ped = fmaf(acc[i][q], a_d[j0 + q], ped);
            }
            pes += __shfl_xor(pes, 1, 64);
            ped += __shfl_xor(ped, 1, 64);
            s0[i] = pes; s1[i] = ped;
        }
        if ((tc & 1) == 0) {
            int h = tc >> 1;
#pragma unroll
            for (int i = 0; i < 4; ++i) {
                int n = base + tr * 4 + i;
                if (n < N_NODES) {
                    es[n * NH + h] = s0[i];
                    ed[n * NH + h] = s1[i];
                }
            }
        }
    }
}

// ---------------------------------------------------------------------------
// weight prep body: Wp = gw @ rw (64x64), bp = gb @ rw + rb.  smem: 8192 floats
// ---------------------------------------------------------------------------
__device__ __forceinline__
void weight_prep_body(float* smem,
                      const float* __restrict__ gw, const float* __restrict__ gb,
                      const float* __restrict__ rw, const float* __restrict__ rb,
                      float* __restrict__ Wp, float* __restrict__ bp)
{
    float* A = smem;           // 4096
    float* B = smem + 4096;    // 4096
    int t = threadIdx.x;
    {
        const float4* ga = (const float4*)gw;
        const float4* rA = (const float4*)rw;
        float4* dA = (float4*)A; float4* dB = (float4*)B;
        for (int i = t; i < 1024; i += 256) { dA[i] = ga[i]; dB[i] = rA[i]; }
    }
    __syncthreads();
    for (int e = t * 16; e < t * 16 + 16; ++e) {
        int k = e >> 6, j = e & 63;
        float acc = 0.f;
#pragma unroll 8
        for (int m = 0; m < 64; ++m) acc = fmaf(A[k * 64 + m], B[m * 64 + j], acc);
        Wp[e] = acc;
    }
    if (t < 64) {
        float acc = rb[t];
#pragma unroll 8
        for (int m = 0; m < 64; ++m) acc = fmaf(gb[m], B[m * 64 + t], acc);
        bp[t] = acc;
    }
}

// ---------------------------------------------------------------------------
// UNION 1: weight_prep x2  ∪  gemm1 tiles [0,T1)  ∪  hist+rank (2-wide unroll)
// ---------------------------------------------------------------------------
__global__ __launch_bounds__(256)
void u1_fused(const float* __restrict__ x, const float* __restrict__ W1,
              bfu* __restrict__ B0, const float* __restrict__ as1,
              const float* __restrict__ ad1, float* __restrict__ es,
              float* __restrict__ ed,
              const int* __restrict__ ei, int* __restrict__ cnt,
              int* __restrict__ rank,
              const float* __restrict__ gc_w, const float* __restrict__ gc_b,
              const float* __restrict__ rc_w, const float* __restrict__ rc_b,
              const float* __restrict__ gt_w, const float* __restrict__ gt_b,
              const float* __restrict__ rt_w, const float* __restrict__ rt_b,
              float* __restrict__ Wcp, float* __restrict__ bcp,
              float* __restrict__ Wtp, float* __restrict__ btp)
{
    __shared__ __align__(16) float smem[12544];
    int b = blockIdx.x;
    if (b < 2) {
        if (b == 0) weight_prep_body(smem, gc_w, gc_b, rc_w, rc_b, Wcp, bcp);
        else        weight_prep_body(smem, gt_w, gt_b, rt_w, rt_b, Wtp, btp);
        return;
    }
    int u = b - 2;
    int stripe = u / 7, r = u % 7;
    if (r < 3) {
        gemm_tile_body<float, FIN, 1>(smem, stripe * 3 + r, x, W1, B0, as1, ad1, es, ed);
    } else {
        int idx = stripe * 4 + (r - 3);
        int t = threadIdx.x;
        const int STR = U1_HISTB * 256;
        for (int e = idx * 256 + t; e < E_EDGES; e += 2 * STR) {
            int e1 = e + STR;
            int d0 = ei[E_EDGES + e];
            int r0 = atomicAdd(&cnt[d0], 1);
            int r1 = 0;
            bool has1 = e1 < E_EDGES;
            if (has1) r1 = atomicAdd(&cnt[ei[E_EDGES + e1]], 1);
            rank[e] = r0;
            if (has1) rank[e1] = r1;
        }
    }
}

// ---------------------------------------------------------------------------
// UNION 2: atomic-free scatter  ∪  gemm1 tiles [T1,NBLK64)  ∪  self-slot mark
// ---------------------------------------------------------------------------
__global__ __launch_bounds__(256)
void u2_fused(const float* __restrict__ x, const float* __restrict__ W1,
              bfu* __restrict__ B0, const float* __restrict__ as1,
              const float* __restrict__ ad1, float* __restrict__ es,
              float* __restrict__ ed,
              const int* __restrict__ ei, const int* __restrict__ rank,
              const int* __restrict__ offs,
              int* __restrict__ csr)
{
    __shared__ __align__(16) float smem[12544];
    int b = blockIdx.x;
    int stripe = b / 11, r = b % 11;
    int t = threadIdx.x;
    if (r < 8) {
        int e = (stripe * 8 + r) * 256 + t;
        if (e < E_EDGES) {
            int s = ei[e], d = ei[E_EDGES + e];
            csr[offs[d] + rank[e]] = s;
        }
    } else if (r < 10) {
        int tile = T1 + stripe * 2 + (r - 8);
        if (tile < NBLK64)
            gemm_tile_body<float, FIN, 1>(smem, tile, x, W1, B0, as1, ad1, es, ed);
    } else {
        int n = stripe * 256 + t;
        if (n < N_NODES) {
            csr[offs[n + 1] - 1] = n | SELF_FLAG;  // self loop ALWAYS last slot
        }
    }
}

// ---------------------------------------------------------------------------
// UNION 3 (fused): dual GEMM (P1,P2 = H @ ea_w1 halves)  +  node attention,
// both from ONE staged H tile.  smem: Ws[8192] | rows[64*68] = 12544 floats.
// After the dual k-loop, Ws is re-staged with na_w1/na_w2.
// ---------------------------------------------------------------------------
__global__ __launch_bounds__(256)
void u3_fused(const bfu* __restrict__ in,
              const float* __restrict__ na_w1, const float* __restrict__ na_b1,
              const float* __restrict__ na_w2, const float* __restrict__ na_b2,
              float2* __restrict__ al2,
              const float* __restrict__ ea_w1,
              bfu* __restrict__ out0, bfu* __restrict__ out1)
{
    __shared__ __align__(16) float smem[12544];
    float* Ws   = smem;            // 8192 floats
    float* rows = smem + 8192;     // 64*68
    int t = threadIdx.x;
    int base = blockIdx.x * 64;
    const float* W0 = ea_w1;
    const float* W1 = ea_w1 + 64 * 64;
    {
        const float4* W0v = (const float4*)W0;
        const float4* W1v = (const float4*)W1;
        float4* Wsv = (float4*)Ws;
        for (int i = t; i < 1024; i += 256) { Wsv[i] = W0v[i]; Wsv[1024 + i] = W1v[i]; }
    }
    for (int i = t; i < 64 * 8; i += 256) {
        int r = i >> 3, c = (i & 7) * 8;
        int n = base + r;
        uint4 v = make_uint4(0, 0, 0, 0);
        if (n < N_NODES) v = *(const uint4*)(in + (size_t)n * 64 + c);
        float* dp = rows + r * 68 + c;
        *(float4*)dp       = make_float4(bflo(v.x), bfhi(v.x), bflo(v.y), bfhi(v.y));
        *(float4*)(dp + 4) = make_float4(bflo(v.z), bfhi(v.z), bflo(v.w), bfhi(v.w));
    }
    __syncthreads();
    {
        int tr = t >> 4, tc = t & 15;
        float a0[4][4] = {}, a1[4][4] = {};
        const float4* Wsv = (const float4*)Ws;
        const float4* R4 = (const float4*)rows;       // stride 17 float4s
#pragma unroll 2
        for (int k = 0; k < 64; k += 4) {
            float4 p0 = Wsv[(k + 0) * 16 + tc];
            float4 p1 = Wsv[(k + 1) * 16 + tc];
            float4 p2 = Wsv[(k + 2) * 16 + tc];
            float4 p3 = Wsv[(k + 3) * 16 + tc];
            float4 q0 = Wsv[1024 + (k + 0) * 16 + tc];
            float4 q1 = Wsv[1024 + (k + 1) * 16 + tc];
            float4 q2 = Wsv[1024 + (k + 2) * 16 + tc];
            float4 q3 = Wsv[1024 + (k + 3) * 16 + tc];
            int kq = k >> 2;
#pragma unroll
            for (int i = 0; i < 4; ++i) {
                float4 r = R4[(tr * 4 + i) * 17 + kq];
                a0[i][0] = fmaf(r.x, p0.x, fmaf(r.y, p1.x, fmaf(r.z, p2.x, fmaf(r.w, p3.x, a0[i][0]))));
                a0[i][1] = fmaf(r.x, p0.y, fmaf(r.y, p1.y, fmaf(r.z, p2.y, fmaf(r.w, p3.y, a0[i][1]))));
                a0[i][2] = fmaf(r.x, p0.z, fmaf(r.y, p1.z, fmaf(r.z, p2.z, fmaf(r.w, p3.z, a0[i][2]))));
                a0[i][3] = fmaf(r.x, p0.w, fmaf(r.y, p1.w, fmaf(r.z, p2.w, fmaf(r.w, p3.w, a0[i][3]))));
                a1[i][0] = fmaf(r.x, q0.x, fmaf(r.y, q1.x, fmaf(r.z, q2.x, fmaf(r.w, q3.x, a1[i][0]))));
                a1[i][1] = fmaf(r.x, q0.y, fmaf(r.y, q1.y, fmaf(r.z, q2.y, fmaf(r.w, q3.y, a1[i][1]))));
                a1[i][2] = fmaf(r.x, q0.z, fmaf(r.y, q1.z, fmaf(r.z, q2.z, fmaf(r.w, q3.z, a1[i][2]))));
                a1[i][3] = fmaf(r.x, q0.w, fmaf(r.y, q1.w, fmaf(r.z, q2.w, fmaf(r.w, q3.w, a1[i][3]))));
            }
        }
        int j0 = tc * 4;
#pragma unroll
        for (int i = 0; i < 4; ++i) {
            int n = base + tr * 4 + i;
            if (n >= N_NODES) continue;
            ushort4 o0, o1;
            o0.x = f2bf(a0[i][0]); o0.y = f2bf(a0[i][1]);
            o0.z = f2bf(a0[i][2]); o0.w = f2bf(a0[i][3]);
            o1.x = f2bf(a1[i][0]); o1.y = f2bf(a1[i][1]);
            o1.z = f2bf(a1[i][2]); o1.w = f2bf(a1[i][3]);
            *(ushort4*)(out0 + (size_t)n * 64 + j0) = o0;
            *(ushort4*)(out1 + (size_t)n * 64 + j0) = o1;
        }
    }
    // ---- node attention from the SAME rows tile ----
    __syncthreads();                 // everyone done reading Ws
    {
        const float4* w1v = (const float4*)na_w1;
        float4* dst = (float4*)Ws;
        for (int i = t; i < 512; i += 256) dst[i] = w1v[i];
        if (t < 64) Ws[2048 + t] = na_w2[t];
    }
    __syncthreads();
    {
        int tr = t >> 3;
        int tc = t & 7;
        float4 bv = *(const float4*)(na_b1 + tc * 4);
        float4 acc0 = bv, acc1 = bv;
        const float4* w1sv = (const float4*)Ws;
#pragma unroll 8
        for (int k = 0; k < 64; ++k) {
            float4 w = w1sv[k * 8 + tc];
            float r0 = rows[tr * 68 + k];
            float r1 = rows[(tr + 32) * 68 + k];
            acc0.x = fmaf(r0, w.x, acc0.x); acc0.y = fmaf(r0, w.y, acc0.y);
            acc0.z = fmaf(r0, w.z, acc0.z); acc0.w = fmaf(r0, w.w, acc0.w);
            acc1.x = fmaf(r1, w.x, acc1.x); acc1.y = fmaf(r1, w.y, acc1.y);
            acc1.z = fmaf(r1, w.z, acc1.z); acc1.w = fmaf(r1, w.w, acc1.w);
        }
        float z00 = 0.f, z01 = 0.f, z10 = 0.f, z11 = 0.f;
        float h0, w20, w21;
        int j0 = tc * 4;
#pragma unroll
        for (int q = 0; q < 4; ++q) {
            float a0q = q == 0 ? acc0.x : q == 1 ? acc0.y : q == 2 ? acc0.z : acc0.w;
            float a1q = q == 0 ? acc1.x : q == 1 ? acc1.y : q == 2 ? acc1.z : acc1.w;
            w20 = Ws[2048 + (j0 + q) * 2]; w21 = Ws[2048 + (j0 + q) * 2 + 1];
            h0 = fmaxf(a0q, 0.f);
            z00 = fmaf(h0, w20, z00); z01 = fmaf(h0, w21, z01);
            h0 = fmaxf(a1q, 0.f);
            z10 = fmaf(h0, w20, z10); z11 = fmaf(h0, w21, z11);
        }
#pragma unroll
        for (int o = 1; o < 8; o <<= 1) {
            z00 += __shfl_xor(z00, o, 64); z01 += __shfl_xor(z01, o, 64);
            z10 += __shfl_xor(z10, o, 64); z11 += __shfl_xor(z11, o, 64);
        }
        if (tc == 0) {
            int n0 = base + tr, n1 = base + tr + 32;
            if (n0 < N_NODES) {
                float zz0 = z00 + na_b2[0], zz1 = z01 + na_b2[1];
                float mx = fmaxf(zz0, zz1);
                float e0 = __expf(zz0 - mx), e1 = __expf(zz1 - mx);
                float ss = e0 + e1;
                al2[n0] = make_float2(e0 / ss, e1 / ss);
            }
            if (n1 < N_NODES) {
                float zz0 = z10 + na_b2[0], zz1 = z11 + na_b2[1];
                float mx = fmaxf(zz0, zz1);
                float e0 = __expf(zz0 - mx), e1 = __expf(zz1 - mx);
                float ss = e0 + e1;
                al2[n1] = make_float2(e0 / ss, e1 / ss);
            }
        }
    }
}

// ---------------------------------------------------------------------------
// gemm for GAT layer 2 (standalone)
// ---------------------------------------------------------------------------
__global__ __launch_bounds__(256)
void gemm_tile_k64(const bfu* __restrict__ in, const float* __restrict__ W,
                   bfu* __restrict__ outB,
                   const float* __restrict__ a_s, const float* __restrict__ a_d,
                   float* __restrict__ es, float* __restrict__ ed)
{
    __shared__ __align__(16) float smem[64 * 64 + 64 * 68];
    gemm_tile_body<bfu, 64, 1>(smem, blockIdx.x, in, W, outB, a_s, a_d, es, ed);
}

// ---------------------------------------------------------------------------
// CSR scan chain: scan1 (local scans + raw block sums + graph boundaries),
// scan23 (each block recomputes its bsum prefix; no serial pass)
// ---------------------------------------------------------------------------
__global__ void csr_scan1(const int* __restrict__ cnt, int* __restrict__ offs,
                          int* __restrict__ bsum, const int* __restrict__ batch,
                          int* __restrict__ glo)
{
    __shared__ int tmp[256];
    int t = threadIdx.x;
    int i = blockIdx.x * 256 + t;
    int v = (i < N_NODES) ? cnt[i] + 1 : 0;
    tmp[t] = v; __syncthreads();
#pragma unroll
    for (int o = 1; o < 256; o <<= 1) {
        int a = (t >= o) ? tmp[t - o] : 0;
        __syncthreads();
        tmp[t] += a;
        __syncthreads();
    }
    if (i < N_NODES) offs[i] = tmp[t] - v;
    if (t == 255) bsum[blockIdx.x] = tmp[255];
    // graph boundaries: glo[g] = lower_bound(batch, g), g = 0..NG
    if (blockIdx.x == 0 && t <= NG) {
        int l = 0, r = N_NODES;
        while (l < r) { int m = (l + r) >> 1; if (batch[m] < t) l = m + 1; else r = m; }
        glo[t] = l;
    }
}

__global__ void csr_scan23(int* __restrict__ offs, const int* __restrict__ bsum)
{
    __shared__ int tmp[256];
    int b = blockIdx.x;
    int t = threadIdx.x;
    int s = 0;
    for (int j = t; j < b; j += 256) s += bsum[j];
    tmp[t] = s; __syncthreads();
#pragma unroll
    for (int o = 128; o > 0; o >>= 1) {
        if (t < o) tmp[t] += tmp[t + o];
        __syncthreads();
    }
    int prefix = tmp[0];
    int i = b * 256 + t;
    if (i < N_NODES) offs[i] += prefix;
    if (i == 0) offs[N_NODES] = E2;
}

// ---------------------------------------------------------------------------
// Fused GAT aggregate, slot-per-node: wave = 4 nodes; 16 lanes per node walk
// the node's edges serially.  Each lane's den[h] is complete => NO cross-lane
// reduce; stores are full-width (64 lanes = 4 rows).  Self edge included.
// ---------------------------------------------------------------------------
template<int ELU>
__global__ void gat_aggregate4(const int* __restrict__ offs, const int* __restrict__ csr,
                               const float* __restrict__ es, const float* __restrict__ ed,
                               const bfu* __restrict__ hsrcB, const float* __restrict__ bias,
                               bfu* __restrict__ outB)
{
    int w = threadIdx.x >> 6;          // wave in block
    int lane = threadIdx.x & 63;
    int slot = lane >> 4;              // node slot 0..3
    int fl = lane & 15;                // feature chunk: features fl*4 .. fl*4+3
    int h  = fl >> 1;                  // head
    int n = (blockIdx.x * 4 + w) * 4 + slot;
    if (n >= N_NODES) return;
    float4 bv = *(const float4*)(bias + fl * 4);
    int beg = offs[n], end = offs[n + 1];
    float edv = ed[n * NH + h];
    float den = 0.f;
    float4 acc = make_float4(0.f, 0.f, 0.f, 0.f);
    int p = beg;
    for (; p + 1 < end; p += 2) {
        int s0 = csr[p] & SRC_MASK;
        int s1 = csr[p + 1] & SRC_MASK;
        float ex0 = __expf(lrelu(es[s0 * NH + h] + edv));
        float ex1 = __expf(lrelu(es[s1 * NH + h] + edv));
        den += ex0 + ex1;
        ushort4 ra = *(const ushort4*)(hsrcB + (size_t)s0 * HD + fl * 4);
        ushort4 rb = *(const ushort4*)(hsrcB + (size_t)s1 * HD + fl * 4);
        acc.x = fmaf(bf2f(ra.x), ex0, fmaf(bf2f(rb.x), ex1, acc.x));
        acc.y = fmaf(bf2f(ra.y), ex0, fmaf(bf2f(rb.y), ex1, acc.y));
        acc.z = fmaf(bf2f(ra.z), ex0, fmaf(bf2f(rb.z), ex1, acc.z));
        acc.w = fmaf(bf2f(ra.w), ex0, fmaf(bf2f(rb.w), ex1, acc.w));
    }
    if (p < end) {
        int s = csr[p] & SRC_MASK;
        float ex = __expf(lrelu(es[s * NH + h] + edv));
        den += ex;
        ushort4 rb = *(const ushort4*)(hsrcB + (size_t)s * HD + fl * 4);
        acc.x = fmaf(bf2f(rb.x), ex, acc.x);
        acc.y = fmaf(bf2f(rb.y), ex, acc.y);
        acc.z = fmaf(bf2f(rb.z), ex, acc.z);
        acc.w = fmaf(bf2f(rb.w), ex, acc.w);
    }
    float inv = 1.f / (den + 1e-16f);
    float v0 = acc.x * inv + bv.x;
    float v1 = acc.y * inv + bv.y;
    float v2 = acc.z * inv + bv.z;
    float v3 = acc.w * inv + bv.w;
    if (ELU) {
        v0 = v0 > 0.f ? v0 : (__expf(v0) - 1.f);
        v1 = v1 > 0.f ? v1 : (__expf(v1) - 1.f);
        v2 = v2 > 0.f ? v2 : (__expf(v2) - 1.f);
        v3 = v3 > 0.f ? v3 : (__expf(v3) - 1.f);
    }
    ushort4 ov;
    ov.x = f2bf(v0); ov.y = f2bf(v1); ov.z = f2bf(v2); ov.w = f2bf(v3);
    *(ushort4*)(outB + (size_t)n * HD + fl * 4) = ov;
}

// ---------------------------------------------------------------------------
// edge attention, per-NODE, NPW nodes per wave (setup amortized): 8 edge-slots
// x 8 feature-lanes.  Wave-invariant weights/biases loaded ONCE per wave; the
// wave then walks NPW consecutive nodes.  Pass 1 stages beta in per-wave LDS.
// Pass 2 writes scaled {beta*dis[d]} coalesced, incl. self slot.
// prod2[n] = {dis*alpha}.  Overflow (deg>ECAP) falls back to global staging.
// ---------------------------------------------------------------------------
__global__ __launch_bounds__(256)
void edge_att_node(const int* __restrict__ offs, const int* __restrict__ csr,
                   const bfu* __restrict__ P1b, const bfu* __restrict__ P2b,
                   const float* __restrict__ b1, const float* __restrict__ w2,
                   const float* __restrict__ b2,
                   const float2* __restrict__ al2,
                   float2* __restrict__ beta2,
                   float2* __restrict__ prod2)
{
    __shared__ float2 bbuf[4][ECAP];             // 8 KB: per-wave beta staging
    int w = threadIdx.x >> 6;                    // wave id in block
    int lane = threadIdx.x & 63;
    int nbase = (blockIdx.x * 4 + w) * NPW;
    if (nbase >= N_NODES) return;
    int slot = lane >> 3, q = lane & 7;
    // ---- wave-invariant setup (once) ----
    const float4* pb = (const float4*)(b1 + q * 8);
    const float4* pw = (const float4*)(w2 + q * 16);
    float4 c0 = pb[0], c1 = pb[1];
    float4 w0 = pw[0], w1v = pw[1], w2v = pw[2], w3v = pw[3];
    float wd0 = w0.x - w0.y,   wd1 = w0.z - w0.w;
    float wd2 = w1v.x - w1v.y, wd3 = w1v.z - w1v.w;
    float wd4 = w2v.x - w2v.y, wd5 = w2v.z - w2v.w;
    float wd6 = w3v.x - w3v.y, wd7 = w3v.z - w3v.w;
    float zbd = b2[0] - b2[1];
    for (int j = 0; j < NPW; ++j) {
        int n = nbase + j;
        if (n >= N_NODES) return;
        uint4 U2 = *(const uint4*)(P2b + (size_t)n * 64 + q * 8);
        float d0 = bflo(U2.x) + c0.x, d1 = bfhi(U2.x) + c0.y;
        float d2 = bflo(U2.y) + c0.z, d3 = bfhi(U2.y) + c0.w;
        float d4 = bflo(U2.z) + c1.x, d5 = bfhi(U2.z) + c1.y;
        float d6 = bflo(U2.w) + c1.z, d7 = bfhi(U2.w) + c1.w;
        int beg = offs[n], endr = offs[n + 1] - 1;   // real edges only
        int m = endr - beg;
        float dc = 0.f, dt = 0.f;
        for (int p = beg + slot; p < endr; p += 8) {
            int s = csr[p];                           // real edge: raw src index
            uint4 U1 = *(const uint4*)(P1b + (size_t)s * 64 + q * 8);
            float h0 = fmaxf(bflo(U1.x) + d0, 0.f);
            float h1 = fmaxf(bfhi(U1.x) + d1, 0.f);
            float h2 = fmaxf(bflo(U1.y) + d2, 0.f);
            float h3 = fmaxf(bfhi(U1.y) + d3, 0.f);
            float h4 = fmaxf(bflo(U1.z) + d4, 0.f);
            float h5 = fmaxf(bfhi(U1.z) + d5, 0.f);
            float h6 = fmaxf(bflo(U1.w) + d6, 0.f);
            float h7 = fmaxf(bfhi(U1.w) + d7, 0.f);
            float z = fmaf(h0, wd0, fmaf(h1, wd1, fmaf(h2, wd2, fmaf(h3, wd3,
                      fmaf(h4, wd4, fmaf(h5, wd5, fmaf(h6, wd6, h7 * wd7)))))));
            z += __shfl_xor(z, 1, 64);
            z += __shfl_xor(z, 2, 64);
            z += __shfl_xor(z, 4, 64);
            if (q == 0) {
                z += zbd;
                // beta_c = sigmoid(z), beta_t = sigmoid(-z), numerically stable
                float e = __expf(-fabsf(z));
                float inv = 1.f / (1.f + e);
                float bx = z >= 0.f ? inv : e * inv;
                float by = z >= 0.f ? e * inv : inv;
                int idx = p - beg;
                if (idx < ECAP) bbuf[w][idx] = make_float2(bx, by);
                else            beta2[p]    = make_float2(bx, by);  // rare
                dc += bx; dt += by;
            }
        }
        // reduce across the 8 slots (only q==0 lanes hold nonzero partials)
        dc += __shfl_xor(dc, 8, 64);  dt += __shfl_xor(dt, 8, 64);
        dc += __shfl_xor(dc, 16, 64); dt += __shfl_xor(dt, 16, 64);
        dc += __shfl_xor(dc, 32, 64); dt += __shfl_xor(dt, 32, 64);
        dc = __shfl(dc, 0, 64); dt = __shfl(dt, 0, 64);
        dc += 1.f; dt += 1.f;                         // self loop contribution
        float ic = rsqrtf(fmaxf(dc, 1e-20f));
        float it = rsqrtf(fmaxf(dt, 1e-20f));
        if (lane == 0) {
            float2 al = al2[n];
            prod2[n] = make_float2(ic * al.x, it * al.y);
        }
        if (m > ECAP)                                 // order overflow stores
            asm volatile("s_waitcnt vmcnt(0)" ::: "memory");
        // pass 2: coalesced scaled stores; idx==m is the self slot ({ic,it})
        for (int idx = lane; idx <= m; idx += 64) {
            float2 v = (idx == m) ? make_float2(1.f, 1.f)
                     : (idx < ECAP) ? bbuf[w][idx] : beta2[beg + idx];
            beta2[beg + idx] = make_float2(v.x * ic, v.y * it);
        }
    }
}

// ---------------------------------------------------------------------------
// FUSED GCN aggregate + graph readout:
// w_c = prod_c[s] * beta2_c[p]   (beta2 already contains beta*dis[d]; self
// slots contain dis[d]).  No csrd, no dis2, no flag select.
// ---------------------------------------------------------------------------
__global__ __launch_bounds__(256)
void gcn_readout_fused(const int* __restrict__ offs, const int* __restrict__ csr,
                       const int* __restrict__ glo,
                       const bfu* __restrict__ HB,
                       const float2* __restrict__ beta2,
                       const float2* __restrict__ prod2,
                       float* __restrict__ Pc, float* __restrict__ Pt)
{
    int g = blockIdx.x / GB, b = blockIdx.x % GB;
    int t = threadIdx.x;
    int pbeg = offs[glo[g]], pend = offs[glo[g + 1]];
    int total = pend - pbeg;
    int chunk = (total + GB - 1) / GB;
    int start = pbeg + b * chunk;
    int end = start + chunk;
    if (end > pend) end = pend;
    if (start > pend) start = pend;
    int slot = t >> 4, fl = t & 15;
    float4 a1 = make_float4(0.f, 0.f, 0.f, 0.f);
    float4 a2 = make_float4(0.f, 0.f, 0.f, 0.f);
    int p = start + slot;
    for (; p + 48 < end; p += 64) {
#pragma unroll
        for (int j = 0; j < 4; ++j) {
            int pp = p + j * 16;
            int s = csr[pp] & SRC_MASK;
            float2 bb = beta2[pp];
            float2 pr = prod2[s];
            float wc = pr.x * bb.x;
            float wt = pr.y * bb.y;
            ushort4 r0 = *(const ushort4*)(HB + (size_t)s * HD + fl * 4);
            float f0 = bf2f(r0.x), f1 = bf2f(r0.y), f2 = bf2f(r0.z), f3 = bf2f(r0.w);
            a1.x = fmaf(f0, wc, a1.x); a1.y = fmaf(f1, wc, a1.y);
            a1.z = fmaf(f2, wc, a1.z); a1.w = fmaf(f3, wc, a1.w);
            a2.x = fmaf(f0, wt, a2.x); a2.y = fmaf(f1, wt, a2.y);
            a2.z = fmaf(f2, wt, a2.z); a2.w = fmaf(f3, wt, a2.w);
        }
    }
    for (; p < end; p += 16) {
        int s = csr[p] & SRC_MASK;
        float2 bb = beta2[p];
        float2 pr = prod2[s];
        float wc = pr.x * bb.x;
        float wt = pr.y * bb.y;
        ushort4 r0 = *(const ushort4*)(HB + (size_t)s * HD + fl * 4);
        float f0 = bf2f(r0.x), f1 = bf2f(r0.y), f2 = bf2f(r0.z), f3 = bf2f(r0.w);
        a1.x = fmaf(f0, wc, a1.x); a1.y = fmaf(f1, wc, a1.y);
        a1.z = fmaf(f2, wc, a1.z); a1.w = fmaf(f3, wc, a1.w);
        a2.x = fmaf(f0, wt, a2.x); a2.y = fmaf(f1, wt, a2.y);
        a2.z = fmaf(f2, wt, a2.z); a2.w = fmaf(f3, wt, a2.w);
    }
    __shared__ float redc[16 * 64], redt[16 * 64];
    *(float4*)(redc + slot * 64 + fl * 4) = a1;
    *(float4*)(redt + slot * 64 + fl * 4) = a2;
    __syncthreads();
    if (t < 64) {
        float sc = 0.f, st = 0.f;
#pragma unroll
        for (int s = 0; s < 16; ++s) { sc += redc[s * 64 + t]; st += redt[s * 64 + t]; }
        Pc[(size_t)blockIdx.x * 64 + t] = sc;
        Pt[(size_t)blockIdx.x * 64 + t] = st;
    }
}

// ---------------------------------------------------------------------------
// final heads: one 64-thread block per graph.
// ---------------------------------------------------------------------------
__global__ __launch_bounds__(64)
void head_final(const float* __restrict__ Pc, const float* __restrict__ Pt,
                const int* __restrict__ glo,
                const float* __restrict__ Wcp, const float* __restrict__ bcp,
                const float* __restrict__ Wtp, const float* __restrict__ btp,
                const float* __restrict__ cc_w1, const float* __restrict__ cc_b1,
                const float* __restrict__ cc_w2, const float* __restrict__ cc_b2,
                const float* __restrict__ ct_w1, const float* __restrict__ ct_b1,
                const float* __restrict__ ct_w2, const float* __restrict__ ct_b2,
                const float* __restrict__ cm_w1, const float* __restrict__ cm_b1,
                const float* __restrict__ cm_w2, const float* __restrict__ cm_b2,
                float* __restrict__ out)
{
    int g = blockIdx.x;
    int t = threadIdx.x;
    __shared__ float scl[64], stl[64], hgc[64], hgt[64], hid[64];
    float sc = 0.f, st = 0.f;
#pragma unroll
    for (int b = 0; b < GB; ++b) {
        sc += Pc[(size_t)(g * GB + b) * 64 + t];
        st += Pt[(size_t)(g * GB + b) * 64 + t];
    }
    scl[t] = sc; stl[t] = st;
    float c = (float)(glo[g + 1] - glo[g]);
    __syncthreads();
    {
        float a = c * bcp[t], bb = c * btp[t];
#pragma unroll 8
        for (int k = 0; k < 64; ++k) {
            a  = fmaf(scl[k], Wcp[k * 64 + t], a);
            bb = fmaf(stl[k], Wtp[k * 64 + t], bb);
        }
        hgc[t] = a; hgt[t] = bb;
        out[3840 + g * 64 + t]  = a;
        out[12032 + g * 64 + t] = bb;
    }
    __syncthreads();
    if (t < 32) {
        float a = cc_b1[t];
#pragma unroll 8
        for (int k = 0; k < 64; ++k) a = fmaf(hgc[k], cc_w1[k * 32 + t], a);
        hid[t] = fmaxf(a, 0.f);
    }
    __syncthreads();
    if (t < NC) {
        float a = cc_b2[t];
#pragma unroll
        for (int k = 0; k < 32; ++k) a = fmaf(hid[k], cc_w2[k * NC + t], a);
        out[g * NC + t] = a;
    }
    __syncthreads();
    if (t < 32) {
        float a = ct_b1[t];
#pragma unroll 8
        for (int k = 0; k < 64; ++k) a = fmaf(hgt[k], ct_w1[k * 32 + t], a);
        hid[t] = fmaxf(a, 0.f);
    }
    __syncthreads();
    if (t < NC) {
        float a = ct_b2[t];
#pragma unroll
        for (int k = 0; k < 32; ++k) a = fmaf(hid[k], ct_w2[k * NC + t], a);
        out[1280 + g * NC + t] = a;
    }
    __syncthreads();
    {
        float a = cm_b1[t];
#pragma unroll 8
        for (int k = 0; k < 64; ++k) {
            a = fmaf(hgc[k], cm_w1[k * 64 + t], a);
            a = fmaf(hgt[k], cm_w1[(64 + k) * 64 + t], a);
        }
        hid[t] = fmaxf(a, 0.f);
    }
    __syncthreads();
    if (t < NC) {
        float a = cm_b2[t];
#pragma unroll 8
        for (int k = 0; k < 64; ++k) a = fmaf(hid[k], cm_w2[k * NC + t], a);
        out[2560 + g * NC + t] = a;
    }
}

// ---------------------------------------------------------------------------
extern "C" void kernel_launch(void* const* d_in, const int* in_sizes, int n_in,
                              void* d_out, int out_size, void* d_ws, size_t ws_size,
                              hipStream_t stream)
{
    const float* x     = (const float*)d_in[0];
    const int*   ei    = (const int*)d_in[1];
    const int*   batch = (const int*)d_in[2];
    const float* W1    = (const float*)d_in[3];
    const float* as1   = (const float*)d_in[4];
    const float* ad1   = (const float*)d_in[5];
    const float* b1    = (const float*)d_in[6];
    const float* W2    = (const float*)d_in[7];
    const float* as2   = (const float*)d_in[8];
    const float* ad2   = (const float*)d_in[9];
    const float* b2    = (const float*)d_in[10];
    const float* na_w1 = (const float*)d_in[11];
    const float* na_b1 = (const float*)d_in[12];
    const float* na_w2 = (const float*)d_in[13];
    const float* na_b2 = (const float*)d_in[14];
    const float* ea_w1 = (const float*)d_in[15];
    const float* ea_b1 = (const float*)d_in[16];
    const float* ea_w2 = (const float*)d_in[17];
    const float* ea_b2 = (const float*)d_in[18];
    const float* gc_w  = (const float*)d_in[19];
    const float* gc_b  = (const float*)d_in[20];
    const float* gt_w  = (const float*)d_in[21];
    const float* gt_b  = (const float*)d_in[22];
    const float* rc_w  = (const float*)d_in[23];
    const float* rc_b  = (const float*)d_in[24];
    const float* rt_w  = (const float*)d_in[25];
    const float* rt_b  = (const float*)d_in[26];
    const float* cc_w1 = (const float*)d_in[27];
    const float* cc_b1 = (const float*)d_in[28];
    const float* cc_w2 = (const float*)d_in[29];
    const float* cc_b2 = (const float*)d_in[30];
    const float* ct_w1 = (const float*)d_in[31];
    const float* ct_b1 = (const float*)d_in[32];
    const float* ct_w2 = (const float*)d_in[33];
    const float* ct_b2 = (const float*)d_in[34];
    const float* cm_w1 = (const float*)d_in[35];
    const float* cm_b1 = (const float*)d_in[36];
    const float* cm_w2 = (const float*)d_in[37];
    const float* cm_b2 = (const float*)d_in[38];
    float* out = (float*)d_out;

    float* ws = (float*)d_ws;
    size_t o = 0;
    const size_t nf = (size_t)N_NODES * HD;
    float* es    = ws + o; o += (size_t)N_NODES * NH;
    float* ed    = ws + o; o += (size_t)N_NODES * NH;
    float2* al2  = (float2*)(ws + o); o += (size_t)N_NODES * 2;
    float2* beta2= (float2*)(ws + o); o += (size_t)E2 * 2;      // {beta_c,beta_t}*dis[d]
    float2* prod2= (float2*)(ws + o); o += (size_t)N_NODES * 2; // {dis*alpha} per node
    bfu* B0      = (bfu*)(ws + o); o += nf / 2; // transform/P1 table
    bfu* B1      = (bfu*)(ws + o); o += nf / 2; // P2 table
    bfu* B2      = (bfu*)(ws + o); o += nf / 2; // H table (bf16)
    bfu* BH1     = (bfu*)(ws + o); o += nf / 2; // H1 table (bf16)
    int* csr     = (int*)(ws + o); o += E2;
    int* offs    = (int*)(ws + o); o += N_NODES + 1;
    float* Pc    = ws + o; o += (size_t)NG * GB * 64;
    float* Pt    = ws + o; o += (size_t)NG * GB * 64;
    float* Wcp   = ws + o; o += 4096;
    float* Wtp   = ws + o; o += 4096;
    float* bcp   = ws + o; o += 64;
    float* btp   = ws + o; o += 64;
    int* glo     = (int*)(ws + o); o += NG + 2;  // graph node boundaries
    // temporaries alias buffers written later:
    int* cnt  = (int*)beta2;   // used in U1+scan1; beta2 written by edge_att later
    int* bsum = (int*)prod2;   // used in scans; prod2 written by edge_att later
    int* rank = (int*)B1;      // written U1, read U2; B1 written in u3 later

    // ---------------- CSR count + GAT1 gemm (first chunk) + weight prep -----
    hipMemsetAsync(cnt, 0, (size_t)N_NODES * 4, stream);
    u1_fused<<<U1_GRID, 256, 0, stream>>>(x, W1, B0, as1, ad1, es, ed,
                                          ei, cnt, rank,
                                          gc_w, gc_b, rc_w, rc_b,
                                          gt_w, gt_b, rt_w, rt_b,
                                          Wcp, bcp, Wtp, btp);
    csr_scan1<<<NSCAN_BLK, 256, 0, stream>>>(cnt, offs, bsum, batch, glo);
    csr_scan23<<<NSCAN_BLK, 256, 0, stream>>>(offs, bsum);

    // ---------------- scatter (atomic-free) + self mark + GAT1 gemm (rest) --
    u2_fused<<<U2_GRID, 256, 0, stream>>>(x, W1, B0, as1, ad1, es, ed,
                                          ei, rank, offs, csr);

    // ---------------- GAT layer 1 aggregate ----------------
    gat_aggregate4<1><<<AG_BLKS, 256, 0, stream>>>(offs, csr, es, ed, B0, b1, BH1);

    // ---------------- GAT layer 2 ----------------
    gemm_tile_k64<<<NBLK64, 256, 0, stream>>>(BH1, W2, B0, as2, ad2, es, ed);
    gat_aggregate4<0><<<AG_BLKS, 256, 0, stream>>>(offs, csr, es, ed, B0, b2, B2);

    // ---------------- fused: edge projections + node attention --------------
    u3_fused<<<NBLK64, 256, 0, stream>>>(B2, na_w1, na_b1, na_w2, na_b2, al2,
                                         ea_w1, B0, B1);

    // ---------------- edge attention + degree + LDS-staged dis[d] fold ------
    edge_att_node<<<EA_BLKS, 256, 0, stream>>>(offs, csr, B0, B1,
                                               ea_b1, ea_w2, ea_b2, al2,
                                               beta2, prod2);

    // ---------------- fused GCN aggregate + readout -------------------------
    gcn_readout_fused<<<NG * GB, 256, 0, stream>>>(offs, csr, glo, B2,
                                                   beta2, prod2, Pc, Pt);

    // ---------------- final heads -------------------------------------------
    head_final<<<NG, 64, 0, stream>>>(Pc, Pt, glo,
                                      Wcp, bcp, Wtp, btp,
                                      cc_w1, cc_b1, cc_w2, cc_b2,
                                      ct_w1, ct_b1, ct_w2, ct_b2,
                                      cm_w1, cm_b1, cm_w2, cm_b2, out);
    (void)in_sizes; (void)n_in; (void)out_size; (void)ws_size;
}